// Round 2
// baseline (333.455 us; speedup 1.0000x reference)
//
#include <hip/hip_runtime.h>

typedef short s16x8 __attribute__((ext_vector_type(8)));
typedef float f32x4 __attribute__((ext_vector_type(4)));
typedef float f4 __attribute__((ext_vector_type(4)));
typedef unsigned short u16x4 __attribute__((ext_vector_type(4)));

#define CEXP 14.426950408889634074f   // 10 * log2(e)

__device__ __forceinline__ unsigned short f2bf(float f) {
    union { float f; unsigned int i; } v; v.f = f;
    unsigned int x = v.i;
    return (unsigned short)((x + 0x7fffu + ((x >> 16) & 1u)) >> 16);  // RNE
}
__device__ __forceinline__ float bf2f(unsigned short u) {
    union { unsigned int i; float f; } v; v.i = ((unsigned int)u) << 16; return v.f;
}

// ---------------------------------------------------------------------------
// k_qkv: qkv = x @ W_qkv  (M=16384, K=128, N=384), fp32 compute.
// cb=0 -> q (bf16, unscaled, [bh][N][32]) + sumsq atomics
// cb=1 -> k (same)
// cb=2 -> v (bf16, transposed [bh][32][N])
// ---------------------------------------------------------------------------
__global__ __launch_bounds__(256, 3) void k_qkv(
    const float* __restrict__ x, const float* __restrict__ Wqkv,
    unsigned short* __restrict__ Qb, unsigned short* __restrict__ Kb,
    unsigned short* __restrict__ Vt, float* __restrict__ sumsq)
{
    __shared__ float xs[64][68];
    __shared__ float wsl[64][128];
    const int tb = blockIdx.x, cb = blockIdx.y;
    const int tid = threadIdx.x, tx = tid & 15, ty = tid >> 4;
    float acc[4][8];
#pragma unroll
    for (int t = 0; t < 4; ++t)
#pragma unroll
        for (int j = 0; j < 8; ++j) acc[t][j] = 0.f;

    for (int kc = 0; kc < 2; ++kc) {
        __syncthreads();
#pragma unroll
        for (int s = 0; s < 4; ++s) {
            int slot = tid + s * 256;
            int r = slot >> 4, c4 = (slot & 15) << 2;
            *(f4*)&xs[r][c4] = *(const f4*)&x[(tb * 64 + r) * 128 + kc * 64 + c4];
        }
#pragma unroll
        for (int s = 0; s < 8; ++s) {
            int slot = tid + s * 256;
            int r = slot >> 5, c4 = (slot & 31) << 2;
            *(f4*)&wsl[r][c4] = *(const f4*)&Wqkv[(kc * 64 + r) * 384 + cb * 128 + c4];
        }
        __syncthreads();
        for (int e = 0; e < 64; ++e) {
            f4 b0 = *(const f4*)&wsl[e][tx * 4];
            f4 b1 = *(const f4*)&wsl[e][64 + tx * 4];
#pragma unroll
            for (int t = 0; t < 4; ++t) {
                float a = xs[ty * 4 + t][e];
#pragma unroll
                for (int j = 0; j < 4; ++j) {
                    acc[t][j]     += a * b0[j];
                    acc[t][4 + j] += a * b1[j];
                }
            }
        }
    }

    const int b = tb >> 6;                    // 64 token-blocks per batch
    const int n0 = (tb & 63) * 64 + ty * 4;   // n within batch
    if (cb < 2) {
        unsigned short* dst = (cb == 0) ? Qb : Kb;
#pragma unroll
        for (int g = 0; g < 2; ++g) {
            int c = g * 64 + tx * 4;
            int h = c >> 5, d = c & 31;
#pragma unroll
            for (int t = 0; t < 4; ++t) {
                u16x4 pk = { f2bf(acc[t][g * 4 + 0]), f2bf(acc[t][g * 4 + 1]),
                             f2bf(acc[t][g * 4 + 2]), f2bf(acc[t][g * 4 + 3]) };
                *(u16x4*)&dst[(size_t)(((b * 4 + h) * 4096) + n0 + t) * 32 + d] = pk;
            }
#pragma unroll
            for (int j = 0; j < 4; ++j) {
                float ss = 0.f;
#pragma unroll
                for (int t = 0; t < 4; ++t) ss += acc[t][g * 4 + j] * acc[t][g * 4 + j];
                ss += __shfl_xor(ss, 16);
                ss += __shfl_xor(ss, 32);
                if ((ty & 3) == 0)
                    atomicAdd(&sumsq[cb * 512 + (b * 4 + h) * 32 + d + j], ss);
            }
        }
    } else {
#pragma unroll
        for (int g = 0; g < 2; ++g) {
            int c = g * 64 + tx * 4;
            int h = c >> 5, d0 = c & 31;
#pragma unroll
            for (int j = 0; j < 4; ++j) {
                u16x4 pk = { f2bf(acc[0][g * 4 + j]), f2bf(acc[1][g * 4 + j]),
                             f2bf(acc[2][g * 4 + j]), f2bf(acc[3][g * 4 + j]) };
                *(u16x4*)&Vt[(size_t)((b * 4 + h) * 32 + d0 + j) * 4096 + n0] = pk;
            }
        }
    }
}

// ---------------------------------------------------------------------------
// k_norm: in-place scale of Qb/Kb by min(rsqrt(sumsq), 1e12)  (== 1/clip(norm,1e-12))
// ---------------------------------------------------------------------------
__global__ __launch_bounds__(256) void k_norm(
    unsigned short* __restrict__ Qb, unsigned short* __restrict__ Kb,
    const float* __restrict__ sumsq)
{
    int t = blockIdx.x * 256 + threadIdx.x;   // 524288 threads, 8 elems each
    int which = t >> 18;
    int ti = t & 0x3ffff;
    unsigned short* arr = which ? Kb : Qb;
    int i8 = ti * 8;
    int d0 = i8 & 31;
    int bh = i8 >> 17;                        // 4096*32 elements per bh
    const float* sq = sumsq + which * 512 + bh * 32 + d0;
    union { uint4 v; unsigned short u[8]; } dat;
    dat.v = *(const uint4*)(arr + i8);
#pragma unroll
    for (int j = 0; j < 8; ++j) {
        float r = fminf(__builtin_amdgcn_rsqf(sq[j]), 1e12f);
        dat.u[j] = f2bf(bf2f(dat.u[j]) * r);
    }
    *(uint4*)(arr + i8) = dat.v;
}

// ---------------------------------------------------------------------------
// k_attn: flash attention per (bh).  Block = 64 q-rows (4 waves x 16 rows),
// j-loop in tiles of 64.  S^T via mfma(A=K rows, B=Q rows) so softmax state is
// per-lane (i = lane&15); PV via mfma(A=V^T rows, B=P) -> O^T, same lane row.
// P tile per wave: 16 rows x 64 bf16, ROW STRIDE 72 shorts (144 B: pad for
// bank spread; stride MUST be >= 64 -- the round-1 stride-40 overlap was the
// correctness bug).
// ---------------------------------------------------------------------------
__global__ __launch_bounds__(256, 4) void k_attn(
    const unsigned short* __restrict__ Qb, const unsigned short* __restrict__ Kb,
    const unsigned short* __restrict__ Vt, float* __restrict__ Og)
{
    __shared__ union {
        struct { unsigned short Kt[64 * 32]; unsigned short P[4][1152]; } s;  // 13312 B
        float epi[4][576];                                                    // 9216 B
    } lds;
    const int tid = threadIdx.x;
    const int wv = tid >> 6, lane = tid & 63;
    const int qd = lane >> 4, nn = lane & 15;
    const int bh = blockIdx.y;
    const int ib = blockIdx.x * 64 + wv * 16;
    const unsigned short* Qbh = Qb + (size_t)bh * 4096 * 32;
    const unsigned short* Kbh = Kb + (size_t)bh * 4096 * 32;
    const unsigned short* Vbh = Vt + (size_t)bh * 32 * 4096;

    s16x8 qfrag = *(const s16x8*)(Qbh + (ib + nn) * 32 + qd * 8);
    f32x4 o0 = {0.f, 0.f, 0.f, 0.f}, o1 = {0.f, 0.f, 0.f, 0.f};
    const f32x4 zro = {0.f, 0.f, 0.f, 0.f};
    float m = -1e30f, l = 0.f;
    unsigned short* Pw = lds.s.P[wv];

    for (int jt = 0; jt < 64; ++jt) {
        const int jb = jt * 64;
        __syncthreads();
        *(uint4*)(lds.s.Kt + tid * 8) = *(const uint4*)(Kbh + jb * 32 + tid * 8);
        __syncthreads();

        // S^T tile: lane holds S[i=nn][j = jb + 16*js + 4*qd + r]
        f32x4 sv[4];
#pragma unroll
        for (int js = 0; js < 4; ++js) {
            s16x8 kf = *(const s16x8*)(lds.s.Kt + (js * 16 + nn) * 32 + qd * 8);
            sv[js] = __builtin_amdgcn_mfma_f32_16x16x32_bf16(kf, qfrag, zro, 0, 0, 0);
        }
        float mt = -1e30f;
#pragma unroll
        for (int js = 0; js < 4; ++js)
#pragma unroll
            for (int r = 0; r < 4; ++r) {
                float z = sv[js][r] * CEXP;   // logits in log2 domain, scale folded
                sv[js][r] = z;
                mt = fmaxf(mt, z);
            }
        mt = fmaxf(mt, __shfl_xor(mt, 16));
        mt = fmaxf(mt, __shfl_xor(mt, 32));
        float mn = fmaxf(m, mt);
        float alpha = __builtin_amdgcn_exp2f(m - mn);
        m = mn;
        float ts = 0.f;
#pragma unroll
        for (int js = 0; js < 4; ++js) {
            float p0 = __builtin_amdgcn_exp2f(sv[js][0] - mn);
            float p1 = __builtin_amdgcn_exp2f(sv[js][1] - mn);
            float p2 = __builtin_amdgcn_exp2f(sv[js][2] - mn);
            float p3 = __builtin_amdgcn_exp2f(sv[js][3] - mn);
            ts += (p0 + p1) + (p2 + p3);
            u16x4 pk = { f2bf(p0), f2bf(p1), f2bf(p2), f2bf(p3) };
            *(u16x4*)(Pw + nn * 72 + js * 16 + qd * 4) = pk;   // row i=nn, stride 72
        }
        ts += __shfl_xor(ts, 16);
        ts += __shfl_xor(ts, 32);
        l = l * alpha + ts;
        o0 *= alpha;
        o1 *= alpha;
#pragma unroll
        for (int kb = 0; kb < 2; ++kb) {
            s16x8 pf = *(const s16x8*)(Pw + nn * 72 + kb * 32 + qd * 8);          // B = P
            s16x8 v0 = *(const s16x8*)(Vbh + (size_t)nn * 4096 + jb + kb * 32 + qd * 8);
            s16x8 v1 = *(const s16x8*)(Vbh + (size_t)(16 + nn) * 4096 + jb + kb * 32 + qd * 8);
            o0 = __builtin_amdgcn_mfma_f32_16x16x32_bf16(v0, pf, o0, 0, 0, 0);
            o1 = __builtin_amdgcn_mfma_f32_16x16x32_bf16(v1, pf, o1, 0, 0, 0);
        }
    }
    float rl = 1.f / l;
    o0 *= rl;
    o1 *= rl;
    __syncthreads();                       // union reuse: all waves out of loop
    float* ep = lds.epi[wv];               // [16 i][36] fp32, cols 0..31 = dd
#pragma unroll
    for (int r = 0; r < 4; ++r) {
        ep[nn * 36 + qd * 4 + r]      = o0[r];   // O[i=nn][dd=4*qd+r]
        ep[nn * 36 + 16 + qd * 4 + r] = o1[r];   // O[i=nn][dd=16+4*qd+r]
    }
    __syncthreads();                       // make cross-lane LDS writes visible
    const int i = lane >> 2, c8 = (lane & 3) * 8;
    f4 w0 = *(const f4*)&ep[i * 36 + c8];
    f4 w1 = *(const f4*)&ep[i * 36 + c8 + 4];
    const int bb = bh >> 2, hh = bh & 3;
    float* dst = Og + (size_t)(bb * 4096 + blockIdx.x * 64 + wv * 16 + i) * 128 + hh * 32 + c8;
    *(f4*)dst = w0;
    *(f4*)(dst + 4) = w1;
}

// ---------------------------------------------------------------------------
// k_out: out = Og @ W_out + b_out  (M=16384, K=128, N=128), fp32.
// ---------------------------------------------------------------------------
__global__ __launch_bounds__(256, 3) void k_out(
    const float* __restrict__ Og, const float* __restrict__ Wout,
    const float* __restrict__ bout, float* __restrict__ out)
{
    __shared__ float xs[64][68];
    __shared__ float wsl[64][128];
    const int tb = blockIdx.x;
    const int tid = threadIdx.x, tx = tid & 15, ty = tid >> 4;
    float acc[4][8];
#pragma unroll
    for (int t = 0; t < 4; ++t)
#pragma unroll
        for (int j = 0; j < 8; ++j) acc[t][j] = 0.f;

    for (int kc = 0; kc < 2; ++kc) {
        __syncthreads();
#pragma unroll
        for (int s = 0; s < 4; ++s) {
            int slot = tid + s * 256;
            int r = slot >> 4, c4 = (slot & 15) << 2;
            *(f4*)&xs[r][c4] = *(const f4*)&Og[(size_t)(tb * 64 + r) * 128 + kc * 64 + c4];
        }
#pragma unroll
        for (int s = 0; s < 8; ++s) {
            int slot = tid + s * 256;
            int r = slot >> 5, c4 = (slot & 31) << 2;
            *(f4*)&wsl[r][c4] = *(const f4*)&Wout[(kc * 64 + r) * 128 + c4];
        }
        __syncthreads();
        for (int e = 0; e < 64; ++e) {
            f4 b0 = *(const f4*)&wsl[e][tx * 4];
            f4 b1 = *(const f4*)&wsl[e][64 + tx * 4];
#pragma unroll
            for (int t = 0; t < 4; ++t) {
                float a = xs[ty * 4 + t][e];
#pragma unroll
                for (int j = 0; j < 4; ++j) {
                    acc[t][j]     += a * b0[j];
                    acc[t][4 + j] += a * b1[j];
                }
            }
        }
    }
    f4 bv0 = *(const f4*)&bout[tx * 4];
    f4 bv1 = *(const f4*)&bout[64 + tx * 4];
#pragma unroll
    for (int t = 0; t < 4; ++t) {
        f4 r0, r1;
#pragma unroll
        for (int j = 0; j < 4; ++j) { r0[j] = acc[t][j] + bv0[j]; r1[j] = acc[t][4 + j] + bv1[j]; }
        float* o = out + (size_t)(tb * 64 + ty * 4 + t) * 128;
        *(f4*)(o + tx * 4) = r0;
        *(f4*)(o + 64 + tx * 4) = r1;
    }
}

// ---------------------------------------------------------------------------
extern "C" void kernel_launch(void* const* d_in, const int* in_sizes, int n_in,
                              void* d_out, int out_size, void* d_ws, size_t ws_size,
                              hipStream_t stream)
{
    const float* x    = (const float*)d_in[0];
    const float* Wqkv = (const float*)d_in[1];
    const float* Wout = (const float*)d_in[2];
    const float* bout = (const float*)d_in[3];
    float* out = (float*)d_out;
    char* ws = (char*)d_ws;
    const size_t MB = 1024 * 1024;
    unsigned short* Qb = (unsigned short*)(ws);             // 4 MB  [16][4096][32] bf16
    unsigned short* Kb = (unsigned short*)(ws + 4 * MB);    // 4 MB
    unsigned short* Vt = (unsigned short*)(ws + 8 * MB);    // 4 MB  [16][32][4096] bf16
    float*          Og = (float*)(ws + 12 * MB);            // 8 MB  [16384][128] fp32
    float*       sumsq = (float*)(ws + 20 * MB);            // 4 KB  [2][16][32] fp32

    hipMemsetAsync(sumsq, 0, 4096, stream);
    hipLaunchKernelGGL(k_qkv, dim3(256, 3), dim3(256), 0, stream, x, Wqkv, Qb, Kb, Vt, sumsq);
    hipLaunchKernelGGL(k_norm, dim3(2048), dim3(256), 0, stream, Qb, Kb, sumsq);
    hipLaunchKernelGGL(k_attn, dim3(64, 16), dim3(256), 0, stream, Qb, Kb, Vt, Og);
    hipLaunchKernelGGL(k_out, dim3(256), dim3(256), 0, stream, Og, Wout, bout, out);
}

// Round 3
// 304.630 us; speedup vs baseline: 1.0946x; 1.0946x over previous
//
#include <hip/hip_runtime.h>

typedef short s16x8 __attribute__((ext_vector_type(8)));
typedef float f32x4 __attribute__((ext_vector_type(4)));
typedef float f4 __attribute__((ext_vector_type(4)));
typedef unsigned short u16x4 __attribute__((ext_vector_type(4)));

#define CEXP 14.426950408889634074f   // 10 * log2(e)

__device__ __forceinline__ unsigned short f2bf(float f) {
    union { float f; unsigned int i; } v; v.f = f;
    unsigned int x = v.i;
    return (unsigned short)((x + 0x7fffu + ((x >> 16) & 1u)) >> 16);  // RNE
}
__device__ __forceinline__ float bf2f(unsigned short u) {
    union { unsigned int i; float f; } v; v.i = ((unsigned int)u) << 16; return v.f;
}

// ---------------------------------------------------------------------------
// k_qkv: qkv = x @ W_qkv  (M=16384, K=128, N=384), fp32 compute.
// cb=0 -> q (bf16, unscaled, [bh][N][32]) + sumsq atomics
// cb=1 -> k (same)
// cb=2 -> v (bf16, transposed [bh][32][N])
// ---------------------------------------------------------------------------
__global__ __launch_bounds__(256, 3) void k_qkv(
    const float* __restrict__ x, const float* __restrict__ Wqkv,
    unsigned short* __restrict__ Qb, unsigned short* __restrict__ Kb,
    unsigned short* __restrict__ Vt, float* __restrict__ sumsq)
{
    __shared__ float xs[64][68];
    __shared__ float wsl[64][128];
    const int tb = blockIdx.x, cb = blockIdx.y;
    const int tid = threadIdx.x, tx = tid & 15, ty = tid >> 4;
    float acc[4][8];
#pragma unroll
    for (int t = 0; t < 4; ++t)
#pragma unroll
        for (int j = 0; j < 8; ++j) acc[t][j] = 0.f;

    for (int kc = 0; kc < 2; ++kc) {
        __syncthreads();
#pragma unroll
        for (int s = 0; s < 4; ++s) {
            int slot = tid + s * 256;
            int r = slot >> 4, c4 = (slot & 15) << 2;
            *(f4*)&xs[r][c4] = *(const f4*)&x[(tb * 64 + r) * 128 + kc * 64 + c4];
        }
#pragma unroll
        for (int s = 0; s < 8; ++s) {
            int slot = tid + s * 256;
            int r = slot >> 5, c4 = (slot & 31) << 2;
            *(f4*)&wsl[r][c4] = *(const f4*)&Wqkv[(kc * 64 + r) * 384 + cb * 128 + c4];
        }
        __syncthreads();
        for (int e = 0; e < 64; ++e) {
            f4 b0 = *(const f4*)&wsl[e][tx * 4];
            f4 b1 = *(const f4*)&wsl[e][64 + tx * 4];
#pragma unroll
            for (int t = 0; t < 4; ++t) {
                float a = xs[ty * 4 + t][e];
#pragma unroll
                for (int j = 0; j < 4; ++j) {
                    acc[t][j]     += a * b0[j];
                    acc[t][4 + j] += a * b1[j];
                }
            }
        }
    }

    const int b = tb >> 6;                    // 64 token-blocks per batch
    const int n0 = (tb & 63) * 64 + ty * 4;   // n within batch
    if (cb < 2) {
        unsigned short* dst = (cb == 0) ? Qb : Kb;
#pragma unroll
        for (int g = 0; g < 2; ++g) {
            int c = g * 64 + tx * 4;
            int h = c >> 5, d = c & 31;
#pragma unroll
            for (int t = 0; t < 4; ++t) {
                u16x4 pk = { f2bf(acc[t][g * 4 + 0]), f2bf(acc[t][g * 4 + 1]),
                             f2bf(acc[t][g * 4 + 2]), f2bf(acc[t][g * 4 + 3]) };
                *(u16x4*)&dst[(size_t)(((b * 4 + h) * 4096) + n0 + t) * 32 + d] = pk;
            }
#pragma unroll
            for (int j = 0; j < 4; ++j) {
                float ss = 0.f;
#pragma unroll
                for (int t = 0; t < 4; ++t) ss += acc[t][g * 4 + j] * acc[t][g * 4 + j];
                ss += __shfl_xor(ss, 16);
                ss += __shfl_xor(ss, 32);
                if ((ty & 3) == 0)
                    atomicAdd(&sumsq[cb * 512 + (b * 4 + h) * 32 + d + j], ss);
            }
        }
    } else {
#pragma unroll
        for (int g = 0; g < 2; ++g) {
            int c = g * 64 + tx * 4;
            int h = c >> 5, d0 = c & 31;
#pragma unroll
            for (int j = 0; j < 4; ++j) {
                u16x4 pk = { f2bf(acc[0][g * 4 + j]), f2bf(acc[1][g * 4 + j]),
                             f2bf(acc[2][g * 4 + j]), f2bf(acc[3][g * 4 + j]) };
                *(u16x4*)&Vt[(size_t)((b * 4 + h) * 32 + d0 + j) * 4096 + n0] = pk;
            }
        }
    }
}

// ---------------------------------------------------------------------------
// k_norm: in-place scale of Qb/Kb by min(rsqrt(sumsq), 1e12).
// Q additionally gets the softmax scale 10*log2(e) folded in, so k_attn's
// QK^T MFMA directly produces log2-domain logits.
// ---------------------------------------------------------------------------
__global__ __launch_bounds__(256) void k_norm(
    unsigned short* __restrict__ Qb, unsigned short* __restrict__ Kb,
    const float* __restrict__ sumsq)
{
    int t = blockIdx.x * 256 + threadIdx.x;   // 524288 threads, 8 elems each
    int which = t >> 18;
    int ti = t & 0x3ffff;
    unsigned short* arr = which ? Kb : Qb;
    const float post = which ? 1.0f : CEXP;
    int i8 = ti * 8;
    int d0 = i8 & 31;
    int bh = i8 >> 17;                        // 4096*32 elements per bh
    const float* sq = sumsq + which * 512 + bh * 32 + d0;
    union { uint4 v; unsigned short u[8]; } dat;
    dat.v = *(const uint4*)(arr + i8);
#pragma unroll
    for (int j = 0; j < 8; ++j) {
        float r = fminf(__builtin_amdgcn_rsqf(sq[j]), 1e12f) * post;
        dat.u[j] = f2bf(bf2f(dat.u[j]) * r);
    }
    *(uint4*)(arr + i8) = dat.v;
}

// ---------------------------------------------------------------------------
// k_attn: flash attention per (bh).  Block = 64 q-rows (4 waves x 16 rows).
// BARRIER-FREE inner loop: K fragments are read directly from global
// (wave covers a contiguous 1KB; K per bh = 256KB, L2-resident) -- the R2
// LDS K-stage had an 8-way bank conflict (permuted lane->chunk map) and two
// __syncthreads per iteration.  P transposes C->B layout through a per-wave
// LDS tile (stride 72 shorts: 2-way access per quarter-wave = free).
// No online max: logits are |z| <~ 0.3 (sequence-axis l2norm), exp2 safe.
// ---------------------------------------------------------------------------
__global__ __launch_bounds__(256, 4) void k_attn(
    const unsigned short* __restrict__ Qb, const unsigned short* __restrict__ Kb,
    const unsigned short* __restrict__ Vt, float* __restrict__ Og)
{
    __shared__ union { unsigned short P[1152]; float epi[576]; } lds[4];  // 2304 B/wave
    const int tid = threadIdx.x;
    const int wv = tid >> 6, lane = tid & 63;
    const int qd = lane >> 4, nn = lane & 15;
    const int bh = blockIdx.y;
    const int ib = blockIdx.x * 64 + wv * 16;
    const unsigned short* Qbh = Qb + (size_t)bh * 4096 * 32;
    const unsigned short* Kbh = Kb + (size_t)bh * 4096 * 32;
    const unsigned short* Vbh = Vt + (size_t)bh * 32 * 4096;

    s16x8 qfrag = *(const s16x8*)(Qbh + (ib + nn) * 32 + qd * 8);
    f32x4 o0 = {0.f, 0.f, 0.f, 0.f}, o1 = {0.f, 0.f, 0.f, 0.f};
    const f32x4 zro = {0.f, 0.f, 0.f, 0.f};
    float l = 0.f;
    unsigned short* Pw = lds[wv].P;

    const unsigned short* kp  = Kbh + nn * 32 + qd * 8;          // += 2048/iter
    const unsigned short* vp0 = Vbh + (size_t)nn * 4096 + qd * 8;        // += 64/iter
    const unsigned short* vp1 = Vbh + (size_t)(16 + nn) * 4096 + qd * 8;

    for (int jt = 0; jt < 64; ++jt) {
        // S^T tile: lane holds z[i=nn][j = jb + 16*js + 4*qd + r] (log2 domain)
        f32x4 sv[4];
#pragma unroll
        for (int js = 0; js < 4; ++js) {
            s16x8 kf = *(const s16x8*)(kp + js * 512);   // rows jb+16js+nn
            sv[js] = __builtin_amdgcn_mfma_f32_16x16x32_bf16(kf, qfrag, zro, 0, 0, 0);
        }
        float ts = 0.f;
#pragma unroll
        for (int js = 0; js < 4; ++js) {
            float p0 = __builtin_amdgcn_exp2f(sv[js][0]);
            float p1 = __builtin_amdgcn_exp2f(sv[js][1]);
            float p2 = __builtin_amdgcn_exp2f(sv[js][2]);
            float p3 = __builtin_amdgcn_exp2f(sv[js][3]);
            ts += (p0 + p1) + (p2 + p3);
            // round-half-up bf16 pack: bits+0x8000, take high halves via v_perm
            unsigned u0 = __float_as_uint(p0) + 0x8000u;
            unsigned u1 = __float_as_uint(p1) + 0x8000u;
            unsigned u2 = __float_as_uint(p2) + 0x8000u;
            unsigned u3 = __float_as_uint(p3) + 0x8000u;
            uint2 pk = { __builtin_amdgcn_perm(u1, u0, 0x07060302u),
                         __builtin_amdgcn_perm(u3, u2, 0x07060302u) };
            *(uint2*)(Pw + nn * 72 + js * 16 + qd * 4) = pk;   // row i=nn, stride 72
        }
        ts += __shfl_xor(ts, 16);
        ts += __shfl_xor(ts, 32);
        l += ts;
#pragma unroll
        for (int kb = 0; kb < 2; ++kb) {
            s16x8 pf = *(const s16x8*)(Pw + nn * 72 + kb * 32 + qd * 8);   // B = P
            s16x8 v0 = *(const s16x8*)(vp0 + kb * 32);
            s16x8 v1 = *(const s16x8*)(vp1 + kb * 32);
            o0 = __builtin_amdgcn_mfma_f32_16x16x32_bf16(v0, pf, o0, 0, 0, 0);
            o1 = __builtin_amdgcn_mfma_f32_16x16x32_bf16(v1, pf, o1, 0, 0, 0);
        }
        kp += 2048;
        vp0 += 64;
        vp1 += 64;
    }
    float rl = 1.f / l;
    o0 *= rl;
    o1 *= rl;
    float* ep = lds[wv].epi;               // per-wave region; no cross-wave hazard
#pragma unroll
    for (int r = 0; r < 4; ++r) {
        ep[nn * 36 + qd * 4 + r]      = o0[r];   // O[i=nn][dd=4*qd+r]
        ep[nn * 36 + 16 + qd * 4 + r] = o1[r];   // O[i=nn][dd=16+4*qd+r]
    }
    const int i = lane >> 2, c8 = (lane & 3) * 8;
    f4 w0 = *(const f4*)&ep[i * 36 + c8];
    f4 w1 = *(const f4*)&ep[i * 36 + c8 + 4];
    const int bb = bh >> 2, hh = bh & 3;
    float* dst = Og + (size_t)(bb * 4096 + blockIdx.x * 64 + wv * 16 + i) * 128 + hh * 32 + c8;
    *(f4*)dst = w0;
    *(f4*)(dst + 4) = w1;
}

// ---------------------------------------------------------------------------
// k_out: out = Og @ W_out + b_out  (M=16384, K=128, N=128), fp32.
// ---------------------------------------------------------------------------
__global__ __launch_bounds__(256, 3) void k_out(
    const float* __restrict__ Og, const float* __restrict__ Wout,
    const float* __restrict__ bout, float* __restrict__ out)
{
    __shared__ float xs[64][68];
    __shared__ float wsl[64][128];
    const int tb = blockIdx.x;
    const int tid = threadIdx.x, tx = tid & 15, ty = tid >> 4;
    float acc[4][8];
#pragma unroll
    for (int t = 0; t < 4; ++t)
#pragma unroll
        for (int j = 0; j < 8; ++j) acc[t][j] = 0.f;

    for (int kc = 0; kc < 2; ++kc) {
        __syncthreads();
#pragma unroll
        for (int s = 0; s < 4; ++s) {
            int slot = tid + s * 256;
            int r = slot >> 4, c4 = (slot & 15) << 2;
            *(f4*)&xs[r][c4] = *(const f4*)&Og[(size_t)(tb * 64 + r) * 128 + kc * 64 + c4];
        }
#pragma unroll
        for (int s = 0; s < 8; ++s) {
            int slot = tid + s * 256;
            int r = slot >> 5, c4 = (slot & 31) << 2;
            *(f4*)&wsl[r][c4] = *(const f4*)&Wout[(kc * 64 + r) * 128 + c4];
        }
        __syncthreads();
        for (int e = 0; e < 64; ++e) {
            f4 b0 = *(const f4*)&wsl[e][tx * 4];
            f4 b1 = *(const f4*)&wsl[e][64 + tx * 4];
#pragma unroll
            for (int t = 0; t < 4; ++t) {
                float a = xs[ty * 4 + t][e];
#pragma unroll
                for (int j = 0; j < 4; ++j) {
                    acc[t][j]     += a * b0[j];
                    acc[t][4 + j] += a * b1[j];
                }
            }
        }
    }
    f4 bv0 = *(const f4*)&bout[tx * 4];
    f4 bv1 = *(const f4*)&bout[64 + tx * 4];
#pragma unroll
    for (int t = 0; t < 4; ++t) {
        f4 r0, r1;
#pragma unroll
        for (int j = 0; j < 4; ++j) { r0[j] = acc[t][j] + bv0[j]; r1[j] = acc[t][4 + j] + bv1[j]; }
        float* o = out + (size_t)(tb * 64 + ty * 4 + t) * 128;
        *(f4*)(o + tx * 4) = r0;
        *(f4*)(o + 64 + tx * 4) = r1;
    }
}

// ---------------------------------------------------------------------------
extern "C" void kernel_launch(void* const* d_in, const int* in_sizes, int n_in,
                              void* d_out, int out_size, void* d_ws, size_t ws_size,
                              hipStream_t stream)
{
    const float* x    = (const float*)d_in[0];
    const float* Wqkv = (const float*)d_in[1];
    const float* Wout = (const float*)d_in[2];
    const float* bout = (const float*)d_in[3];
    float* out = (float*)d_out;
    char* ws = (char*)d_ws;
    const size_t MB = 1024 * 1024;
    unsigned short* Qb = (unsigned short*)(ws);             // 4 MB  [16][4096][32] bf16
    unsigned short* Kb = (unsigned short*)(ws + 4 * MB);    // 4 MB
    unsigned short* Vt = (unsigned short*)(ws + 8 * MB);    // 4 MB  [16][32][4096] bf16
    float*          Og = (float*)(ws + 12 * MB);            // 8 MB  [16384][128] fp32
    float*       sumsq = (float*)(ws + 20 * MB);            // 4 KB  [2][16][32] fp32

    hipMemsetAsync(sumsq, 0, 4096, stream);
    hipLaunchKernelGGL(k_qkv, dim3(256, 3), dim3(256), 0, stream, x, Wqkv, Qb, Kb, Vt, sumsq);
    hipLaunchKernelGGL(k_norm, dim3(2048), dim3(256), 0, stream, Qb, Kb, sumsq);
    hipLaunchKernelGGL(k_attn, dim3(64, 16), dim3(256), 0, stream, Qb, Kb, Vt, Og);
    hipLaunchKernelGGL(k_out, dim3(256), dim3(256), 0, stream, Og, Wout, bout, out);
}